// Round 7
// baseline (1196.103 us; speedup 1.0000x reference)
//
#include <hip/hip_runtime.h>
#include <vector>
#include <cmath>
#include <cstdint>

// ---------------- static model tables ----------------
constexpr int KLc[4]  = {256,192,128,64};     // k_max per l
constexpr int NMLc[4] = {8,6,4,2};            // radial basis per l
constexpr int SHBc[5] = {0,1,4,9,16};         // sh split bases
constexpr int RBBc[5] = {0,8,14,18,20};       // rb split bases
constexpr int FBc[5]  = {0,256,832,1472,1920};// feats flat base per l
constexpr int NCMB = 34, CGTOT = 3436, FTOT = 1920;

struct Combos { int l1[NCMB], l2[NCMB], L[NCMB], cgoff[NCMB], kk[NCMB]; };
constexpr Combos make_combos(){
  Combos c{}; int n=0, cg=0;
  for(int a=0;a<=3;a++)for(int b=0;b<=3;b++){
    int lo=a>b?a-b:b-a, hi=(a+b<3)?(a+b):3;
    for(int L=lo;L<=hi;L++){
      c.l1[n]=a; c.l2[n]=b; c.L[n]=L; c.cgoff[n]=cg;
      int mx=a>b?a:b; if(L>mx) mx=L; c.kk[n]=KLc[mx];
      cg+=(2*a+1)*(2*b+1)*(2*L+1); n++;
    }
  }
  return c;
}
constexpr Combos CB = make_combos();
static_assert(CB.cgoff[NCMB-1] + 7*7*7 == CGTOT, "cg size");

struct Grp { int cnt[4]; int list[4][12]; };
constexpr Grp make_Lg(){ Grp g{}; for(int i=0;i<NCMB;i++){ int L=CB.L[i]; g.list[L][g.cnt[L]++]=i; } return g; }
constexpr Grp LG = make_Lg();     // combos grouped by output L (k_tp)

struct Rows { int sh[64], rb[64], off[64]; };
constexpr Rows make_rows(){ Rows r{}; int i=0;
  for(int l=0;l<4;l++)for(int m=0;m<2*l+1;m++)for(int n=0;n<NMLc[l];n++){
    r.sh[i]=SHBc[l]+m; r.rb[i]=RBBc[l]+n; r.off[i]=FBc[l]+m*KLc[l]+n*32; i++; }
  for(;i<64;i++){ r.sh[i]=0; r.rb[i]=0; r.off[i]=0; }
  return r; }
constexpr Rows RWS = make_rows();

constexpr int iabs_(int x){ return x<0?-x:x; }
__host__ __device__ constexpr bool sl_valid(int l1,int l2,int kt){ return l2<=3-kt && iabs_(l1-l2)<=3-kt; }
__host__ __device__ constexpr int rb_base(int kt,int l1,int l2){
  int base=0;
  for(int p=0;p<4;p++)for(int q=0;q<4;q++){
    if(p==l1 && q==l2) return base;
    if(sl_valid(p,q,kt)) base += (2*p+1)*(2*q+1);
  }
  return base;
}

// ---------------- k_eq v7: shared-code tables (runtime-indexed, tiny I-footprint) ----------------
// KEY FACT: a row (l2,b,kt)'s valid slice set is the EDGE-PREFIX e < SHB[min(3,l2+3-kt)+1].
// So the pair loop is the same 64 static FMAs acc[slot*16+e] += ed[e]*fv[slot] for every wave;
// per-group structure lives in __constant__ tables indexed by g (wave-uniform SGPR).
constexpr int NG=8, CHUNK=64, SPITCH=145, JUNKROW=144, RINGF=1024, NJMAX=64;
constexpr int REGTOT=11264;   // floats: ring 8x1024 | edge 1024 | nb 64  (epilogue: stage 9280 | out 1920)

struct V7 {
  short roff[NG*4];              // feats row offset per (g,slot)
  unsigned short drow[NG*64];    // dump: srow | ph<<12 ; invalid: ph=15
  unsigned char dumpmask[NG];
  unsigned short jcg[NJMAX];     // contraction jobs, sorted by (g,phase)
  unsigned char  jrb[NJMAX], jn12[NJMAX], jnl[NJMAX];
  unsigned short jout[NJMAX], jos[NJMAX];
  short jix[NG*6];
  int njobs;
};
constexpr V7 make_v7(){
  V7 T{};
  // rows (l2,b,kt), ns = prefix length
  int rl2[30],rbb[30],rkt[30],rns[30]; int nrw=0;
  for(int l2=0;l2<4;l2++)for(int kt=0;kt<4-l2;kt++)for(int b=0;b<2*l2+1;b++){
    int l1max=l2+3-kt; if(l1max>3) l1max=3;
    rl2[nrw]=l2; rbb[nrw]=b; rkt[nrw]=kt; rns[nrw]=SHBc[l1max+1]; nrw++;
  }
  // order by ns desc: 24 ns16 rows -> slots 0..2 of all 8 groups; 6 leftovers -> slot 3 of g0..5
  int ord[30]; int no=0;
  for(int pass=0; pass<4; pass++){
    int want=(pass==0)?16:(pass==1)?9:(pass==2)?4:1;
    for(int i=0;i<nrw;i++) if(rns[i]==want) ord[no++]=i;
  }
  int asgG[30], asgS[30];
  for(int i=0;i<nrw;i++){
    if(i<24){ asgG[ord[i]]=i%8; asgS[ord[i]]=i/8; }
    else    { asgG[ord[i]]=i-24; asgS[ord[i]]=3; }
  }
  for(int i=0;i<NG*4;i++) T.roff[i]=0;
  for(int r=0;r<nrw;r++)
    T.roff[asgG[r]*4+asgS[r]] = (short)(FBc[rl2[r]] + rbb[r]*KLc[rl2[r]] + rkt[r]*64);
  for(int g=0;g<NG;g++){ bool h3=false; for(int r=0;r<nrw;r++) if(asgG[r]==g&&asgS[r]==3) h3=true;
    if(!h3) T.roff[g*4+3]=T.roff[g*4+2]; }
  for(int i=0;i<NG*64;i++) T.drow[i]=0xF000;
  for(int r=0;r<nrw;r++){
    const int g=asgG[r], s=asgS[r], l2=rl2[r], b=rbb[r], kt=rkt[r];
    for(int e=0;e<rns[r];e++){
      const int l1=(e==0)?0:(e<4)?1:(e<9)?2:3;
      const int a=e-SHBc[l1];
      const int ph=(kt==0)?(l1<=2?0:1):kt+1;
      const int srow=rb_base(kt,l1,l2)+a*(2*l2+1)+b-(ph==1?144:0);
      T.drow[g*64+s*16+e]=(unsigned short)(srow|(ph<<12));
      T.dumpmask[g]|=(unsigned char)(1<<ph);
    }
  }
  // combo -> group greedy by total job cost
  int cgrp[NCMB]={};
  { bool used[NCMB]={}; long load[NG]={};
    for(int it=0;it<NCMB;it++){
      int best=-1; long bc=-1;
      for(int i=0;i<NCMB;i++) if(!used[i]){
        int mx=CB.l2[i]>CB.L[i]?CB.l2[i]:CB.L[i];
        long c=(long)(2*CB.l1[i]+1)*(2*CB.l2[i]+1)*(2*CB.L[i]+1)*(4-mx);
        if(c>bc){bc=c;best=i;}
      }
      used[best]=true;
      int g=0; for(int j=1;j<NG;j++) if(load[j]<load[g]) g=j;
      cgrp[best]=g; load[g]+=1;
    }
  }
  // jobs sorted by (g, phase)
  int nj=0;
  for(int g=0;g<NG;g++){
    for(int ph=0;ph<5;ph++){
      T.jix[g*6+ph]=(short)nj;
      for(int ci=0;ci<NCMB;ci++){
        if(cgrp[ci]!=g) continue;
        const int l1=CB.l1[ci], l2=CB.l2[ci], L=CB.L[ci];
        int ok=0, kt=0;
        if(ph==0){ ok=(l1<=2); kt=0; }
        else if(ph==1){ ok=(l1==3); kt=0; }
        else { kt=ph-1; ok=(l2<=3-kt)&&(L<=3-kt); }
        if(!ok) continue;
        T.jcg[nj]=(unsigned short)CB.cgoff[ci];
        T.jrb[nj]=(unsigned char)(rb_base(kt,l1,l2)-(ph==1?144:0));
        T.jn12[nj]=(unsigned char)((2*l1+1)*(2*l2+1));
        T.jnl[nj]=(unsigned char)(2*L+1);
        T.jout[nj]=(unsigned short)(FBc[L]+kt*64);
        T.jos[nj]=(unsigned short)KLc[L];
        nj++;
      }
    }
    T.jix[g*6+5]=(short)nj;
  }
  T.njobs=nj;
  return T;
}
static_assert(make_v7().njobs <= NJMAX, "NJMAX");
__constant__ V7 V7T = make_v7();

// waitcnt immediates (gfx9): vmcnt lo[3:0] hi[15:14], expcnt[6:4]=7, lgkmcnt[11:8]=15
constexpr int vmimm(int n){ return (n&15) | ((n>>4)<<14) | (7<<4) | (15<<8); }
__device__ __forceinline__ void gload_lds16(const float* g, float* l){
  __builtin_amdgcn_global_load_lds((const __attribute__((address_space(1))) void*)g,
                                   (__attribute__((address_space(3))) void*)l, 16, 0, 0);
}

// ---------------- host: numpy-legacy RandomState(0) CG ----------------
namespace nprng {
struct MT {
  uint32_t mt[624]; int mti; bool has_g; double g;
  void seed(uint32_t s){ for(int i=0;i<624;i++){ mt[i]=s; s=1812433253u*(s^(s>>30))+(uint32_t)i+1u; } mti=624; has_g=false; g=0.0; }
  uint32_t u32(){
    if(mti>=624){
      for(int i=0;i<624;i++){
        uint32_t y=(mt[i]&0x80000000u)|(mt[(i+1)%624]&0x7fffffffu);
        mt[i]=mt[(i+397)%624]^(y>>1)^((y&1u)?0x9908b0dfu:0u);
      }
      mti=0;
    }
    uint32_t y=mt[mti++];
    y^=y>>11; y^=(y<<7)&0x9d2c5680u; y^=(y<<15)&0xefc60000u; y^=y>>18;
    return y;
  }
  double dbl(){ uint32_t a=u32()>>5, b=u32()>>6; return (a*67108864.0+b)/9007199254740992.0; }
  double gauss(){
    if(has_g){ has_g=false; return g; }
    double f,x1,x2,r2;
    do{ x1=2.0*dbl()-1.0; x2=2.0*dbl()-1.0; r2=x1*x1+x2*x2; }while(r2>=1.0||r2==0.0);
    f=sqrt(-2.0*log(r2)/r2);
    g=f*x1; has_g=true; return f*x2;
  }
};
}
static std::vector<float> build_cg(){
  nprng::MT r; r.seed(0);
  std::vector<float> v; v.reserve(CGTOT);
  for(int l1=0;l1<=3;l1++)for(int l2=0;l2<=3;l2++){
    int lo=l1>l2?l1-l2:l2-l1, hi=(l1+l2<3)?(l1+l2):3;
    for(int L=lo;L<=hi;L++){
      int n=(2*l1+1)*(2*l2+1)*(2*L+1);
      for(int i=0;i<n;i++) v.push_back((float)(r.gauss()*0.2));
    }
  }
  return v;
}

// ---------------- small setup kernels ----------------
__global__ __launch_bounds__(256) void k_cemb(const float* __restrict__ emb_table,
    const int* __restrict__ species, float* __restrict__ cemb, int* __restrict__ counts, int N){
  int i = blockIdx.x*256 + threadIdx.x;
  if(i < N) counts[i] = 0;
  if(i < N*32){ int n = i>>5, c = i&31; cemb[i] = emb_table[species[n]*32 + c]; }
}

__global__ __launch_bounds__(256) void k_hist(const int* __restrict__ centers, int* counts, int P){
  int i = blockIdx.x*256 + threadIdx.x;
  if(i < P) atomicAdd(&counts[centers[i]], 1);
}

__global__ __launch_bounds__(256) void k_scan(const int* __restrict__ counts,
    int* __restrict__ offsets, int* __restrict__ cursor, int N){
  __shared__ int part[256];
  const int t = threadIdx.x;
  const int CH = (N + 255)/256;
  const int lo = t*CH;
  int hi = (t+1)*CH; if(hi > N) hi = N;
  int s = 0;
  for(int i=lo;i<hi;i++) s += counts[i];
  part[t] = s; __syncthreads();
  const int own = s;
  for(int d=1; d<256; d<<=1){
    int v = (t>=d)? part[t-d] : 0;
    __syncthreads();
    part[t] += v;
    __syncthreads();
  }
  int run = part[t] - own;
  for(int i=lo;i<hi;i++){ offsets[i]=run; cursor[i]=run; run += counts[i]; }
  if(t==255) offsets[N] = part[255];
}

__global__ __launch_bounds__(256) void k_scatter(const int* __restrict__ centers,
    int* cursor, int* __restrict__ perm, int P){
  int i = blockIdx.x*256 + threadIdx.x;
  if(i < P){ int c = centers[i]; int pos = atomicAdd(&cursor[c], 1); perm[pos] = i; }
}

// edges + neighbors in perm order (pair-parallel, coalesced writes)
__global__ __launch_bounds__(256) void k_edge(const float* __restrict__ sh, const float* __restrict__ rb,
    const int* __restrict__ perm, const int* __restrict__ nbrs,
    float* __restrict__ edgeP, int* __restrict__ nbP, int P){
  int u = blockIdx.x*256 + threadIdx.x;
  if(u >= P*16) return;
  const int ip = u>>4, i = u&15;
  const int p = perm[ip];
  const int l = (i==0)?0:(i<4)?1:(i<9)?2:3;
  float s = 0.f;
  for(int n=RBBc[l]; n<RBBc[l+1]; n++) s += rb[p*20+n];
  edgeP[u] = sh[p*16+i]*0.1f*s;       // sh * NU_SCALING * rb.sum
  if(i==0) nbP[ip] = nbrs[p];
}

// ---------------- invariant MP ----------------
__global__ __launch_bounds__(256) void k_inv(const float* __restrict__ sh, const float* __restrict__ rb,
    const float* __restrict__ cemb, const int* __restrict__ nbrs, const int* __restrict__ offsets,
    const int* __restrict__ perm, float* __restrict__ feats){
  const int a = blockIdx.x, t = threadIdx.x;
  __shared__ float sh_s[8][16], rb_s[8][20], emb_s[8][32], shrb_s[8][60];
  const int c = t & 31, rg = t >> 5;
  float acc[8];
  #pragma unroll
  for(int j=0;j<8;j++) acc[j] = 0.f;
  const int beg = offsets[a], cnt = offsets[a+1]-beg;
  for(int jb=0; jb<cnt; jb+=8){
    __syncthreads();
    for(int u=t; u<8*36; u+=256){
      int j=u/36, i=u-36*j;
      if(jb+j<cnt){
        int p=perm[beg+jb+j];
        if(i<16) sh_s[j][i]=sh[p*16+i]*0.1f;
        else     rb_s[j][i-16]=rb[p*20+i-16];
      }
    }
    for(int u=t; u<8*32; u+=256){
      int j=u>>5, i=u&31;
      if(jb+j<cnt){ int nb=nbrs[perm[beg+jb+j]]; emb_s[j][i]=cemb[(size_t)nb*32+i]; }
    }
    __syncthreads();
    for(int u=t; u<8*60; u+=256){
      int j=u/60, r=u-60*j;
      if(jb+j<cnt) shrb_s[j][r] = sh_s[j][RWS.sh[r]] * rb_s[j][RWS.rb[r]];
    }
    __syncthreads();
    const int jm = (cnt-jb<8)?(cnt-jb):8;
    for(int j=0;j<jm;j++){
      const float e = emb_s[j][c];
      #pragma unroll
      for(int q=0;q<8;q++){ int r=rg+8*q; if(r<60) acc[q]=fmaf(shrb_s[j][r], e, acc[q]); }
    }
  }
  #pragma unroll
  for(int q=0;q<8;q++){
    int r = rg + 8*q;
    if(r < 60) feats[(size_t)a*FTOT + RWS.off[r] + c] = 0.1f * acc[q];
  }
}

// ---------------- CG iterate: feats = (feats + 0.1*TP(feats,feats)) * cemb ----------------
__global__ __launch_bounds__(256) void k_tp(float* __restrict__ feats, const float* __restrict__ cg,
    const float* __restrict__ cemb){
  const int a = blockIdx.x, t = threadIdx.x;
  __shared__ float f_s[FTOT];
  __shared__ float cemb_s[32];
  float* fa = feats + (size_t)a*FTOT;
  if(t < 32) cemb_s[t] = cemb[(size_t)a*32 + t];
  for(int i=t;i<FTOT;i+=256)  f_s[i]  = fa[i];
  __syncthreads();
  #pragma unroll
  for(int L=0; L<4; L++){
    const int KLL = KLc[L], nL = 2*L+1;
    const int nel = nL*KLL;
    for(int e=t; e<nel; e+=256){
      const int M = e / KLL, k = e - M*KLL;
      float acc = 0.f;
      #pragma unroll
      for(int gi=0; gi<LG.cnt[L]; gi++){
        const int ci = LG.list[L][gi];
        const int l1 = CB.l1[ci], l2 = CB.l2[ci];
        if(k < CB.kk[ci]){
          const int n2 = 2*l2+1;
          #pragma unroll
          for(int aa=0; aa<2*l1+1; aa++){
            const float Av = f_s[FBc[l1] + aa*KLc[l1] + k];
            #pragma unroll
            for(int b=0; b<n2; b++)
              acc += cg[CB.cgoff[ci] + (aa*n2+b)*nL + M] * (Av * f_s[FBc[l2] + b*KLc[l2] + k]);
          }
        }
      }
      fa[FBc[L] + M*KLL + k] = (f_s[FBc[L] + M*KLL + k] + 0.1f*acc) * cemb_s[k & 31];
    }
  }
}

// ---------------- equivariant MP v7: single shared code path ----------------
template<int NL> __device__ __forceinline__ void job_k(const float* __restrict__ slane,
    float* __restrict__ out_s, const float* __restrict__ cg, const int j, const int lane){
  const int cgb=V7T.jcg[j], rbB=V7T.jrb[j], n12=V7T.jn12[j], outB=V7T.jout[j], ostr=V7T.jos[j];
  float oa[NL];
  #pragma unroll
  for(int M=0;M<NL;M++) oa[M]=0.f;
  const float* sp = slane + rbB;
  const float* cp = cg + cgb;
  for(int o=0;o<n12;o++){
    const float sv = sp[o];
    #pragma unroll
    for(int M=0;M<NL;M++) oa[M]=fmaf(cp[o*NL+M], sv, oa[M]);
  }
  #pragma unroll
  for(int M=0;M<NL;M++) atomicAdd(&out_s[outB + M*ostr + lane], oa[M]);
}

__global__ __launch_bounds__(512,4) void k_eq2(const float* __restrict__ edgeP, const int* __restrict__ nbP,
    const int* __restrict__ offsets, const float* __restrict__ featsA, float* __restrict__ featsB,
    const float* __restrict__ cg){
  __shared__ float region[REGTOT];  // 45056 B: ring|edge|nb (main) unioned with stage|out (epilogue)
  const int a = blockIdx.x, t = threadIdx.x, lane = t&63;
  const int g = __builtin_amdgcn_readfirstlane(t>>6);   // wave-uniform -> SGPR
  float* ring   = region + g*RINGF;       // 4 pair-slots x 256 floats, wave-private
  float* edge_s = region + NG*RINGF;      // 64 pairs x 16
  int*   nbs    = (int*)(region + NG*RINGF + CHUNK*16);
  const int rsel = lane>>4;
  const int roffl = V7T.roff[g*4+rsel] + ((lane&15)<<2);  // per-lane gather offset (4 rows x 16B)
  float acc[64];
  #pragma unroll
  for(int i=0;i<64;i++) acc[i]=0.f;
  const int beg = offsets[a], cnt = offsets[a+1]-beg;

  for(int c0=0; c0<cnt; c0+=CHUNK){
    const int clen = (cnt-c0<CHUNK)?(cnt-c0):CHUNK;
    __builtin_amdgcn_s_waitcnt(vmimm(0));   // drain ring prefetches before restage
    __syncthreads();
    for(int u=t; u<CHUNK*16; u+=512){
      const int j=u>>4, i=u&15;
      edge_s[u] = (j<clen) ? edgeP[((size_t)(beg+c0+j)<<4)+i] : 0.f;  // zero-pad kills tail pairs
    }
    if(t < CHUNK){ int jj=t; if(jj>clen-1) jj=clen-1; nbs[t]=nbP[beg+c0+jj]; }
    __syncthreads();
    gload_lds16(featsA + (size_t)nbs[0]*FTOT + roffl, ring + 0*256);           // prime j=0
    gload_lds16(featsA + (size_t)nbs[clen>1?1:0]*FTOT + roffl, ring + 1*256);  // prime j=1
    for(int j=0; j<clen; j++){
      int jn=j+2; if(jn>clen-1) jn=clen-1;
      gload_lds16(featsA + (size_t)nbs[jn]*FTOT + roffl, ring + ((j+2)&3)*256);
      __builtin_amdgcn_s_waitcnt(vmimm(2));  // pair j's slot ready (j+1,j+2 in flight)
      const float* ep = edge_s + j*16;
      const float* rs = ring + (j&3)*256;
      const float fv0=rs[lane], fv1=rs[64+lane], fv2=rs[128+lane], fv3=rs[192+lane];
      #pragma unroll
      for(int q4=0;q4<4;q4++){
        const float4 e4 = *(const float4*)(ep + q4*4);
        #pragma unroll
        for(int r=0;r<4;r++){
          const float fvr = (r==0)?fv0:(r==1)?fv1:(r==2)?fv2:fv3;
          acc[r*16+q4*4+0] = fmaf(e4.x, fvr, acc[r*16+q4*4+0]);
          acc[r*16+q4*4+1] = fmaf(e4.y, fvr, acc[r*16+q4*4+1]);
          acc[r*16+q4*4+2] = fmaf(e4.z, fvr, acc[r*16+q4*4+2]);
          acc[r*16+q4*4+3] = fmaf(e4.w, fvr, acc[r*16+q4*4+3]);
        }
      }
    }
  }
  __builtin_amdgcn_s_waitcnt(vmimm(0));
  __syncthreads();
  // epilogue: LDS region re-purposed as stage (64 lanes x SPITCH) + out accumulator
  float* stage = region;
  float* out_s = region + 64*SPITCH;
  for(int i=t;i<FTOT;i+=512) out_s[i]=0.f;
  float* slane = stage + lane*SPITCH;
  for(int ph=0; ph<5; ph++){
    __syncthreads();
    if(V7T.dumpmask[g] & (1<<ph)){
      #pragma unroll
      for(int e=0;e<64;e++){
        const int dv = V7T.drow[g*64+e];
        const int dst = ((dv>>12)==ph) ? (dv & 0xFFF) : JUNKROW;  // scalar select, no branch
        slane[dst] = acc[e];
      }
    }
    __syncthreads();
    for(int j=V7T.jix[g*6+ph]; j<V7T.jix[g*6+ph+1]; j++){
      const int nL = V7T.jnl[j];
      if(nL==1)      job_k<1>(slane,out_s,cg,j,lane);
      else if(nL==3) job_k<3>(slane,out_s,cg,j,lane);
      else if(nL==5) job_k<5>(slane,out_s,cg,j,lane);
      else           job_k<7>(slane,out_s,cg,j,lane);
    }
  }
  __syncthreads();
  float* ob = featsB + (size_t)a*FTOT;
  for(int i=t;i<FTOT;i+=512) ob[i] = 0.1f*out_s[i];   // MP_SCALING
}

// ---------------- energy readout ----------------
__global__ __launch_bounds__(256) void k_energy(const float* __restrict__ feats,
    const float* __restrict__ wE, const float* __restrict__ bE,
    float* __restrict__ out, int N){
  const int wid = threadIdx.x >> 6, lane = threadIdx.x & 63;
  const int a = blockIdx.x*4 + wid;
  if(a >= N) return;
  float s = 0.f;
  for(int k=lane; k<256; k+=64) s += feats[(size_t)a*FTOT + k] * wE[k];
  #pragma unroll
  for(int off=32; off; off>>=1) s += __shfl_down(s, off, 64);
  if(lane == 0) out[a] = s + bE[0];
}

// ---------------- launcher ----------------
extern "C" void kernel_launch(void* const* d_in, const int* in_sizes, int n_in,
                              void* d_out, int out_size, void* d_ws, size_t ws_size,
                              hipStream_t stream){
  const float* sh        = (const float*)d_in[0];
  const float* rb        = (const float*)d_in[1];
  const float* emb_table = (const float*)d_in[2];
  const float* wE        = (const float*)d_in[3];
  const float* bE        = (const float*)d_in[4];
  const int*   species   = (const int*)d_in[5];
  const int*   centers   = (const int*)d_in[6];
  const int*   nbrs      = (const int*)d_in[7];
  const int N = in_sizes[5];
  const int P = in_sizes[6];

  char* ws = (char*)d_ws; size_t off = 0;
  auto carve = [&](size_t bytes)->void*{
    void* p = ws + off; off = (off + bytes + 255) & ~(size_t)255; return p;
  };
  float* cg_d    = (float*)carve((size_t)CGTOT*4);
  float* cemb    = (float*)carve((size_t)N*32*4);
  int*   counts  = (int*)  carve((size_t)N*4);
  int*   offsets = (int*)  carve((size_t)(N+1)*4);
  int*   cursor  = (int*)  carve((size_t)N*4);
  int*   perm    = (int*)  carve((size_t)P*4);
  int*   nbP     = (int*)  carve((size_t)P*4);
  float* edgeP   = (float*)carve((size_t)P*16*4);
  float* featsA  = (float*)carve((size_t)N*FTOT*4);
  float* featsB  = (float*)carve((size_t)N*FTOT*4);
  (void)ws_size; (void)n_in; (void)out_size;

  static const std::vector<float> cg_host = build_cg();
  hipMemcpyAsync(cg_d, cg_host.data(), (size_t)CGTOT*4, hipMemcpyHostToDevice, stream);

  k_cemb   <<<(N*32 + 255)/256, 256, 0, stream>>>(emb_table, species, cemb, counts, N);
  k_hist   <<<(P + 255)/256,    256, 0, stream>>>(centers, counts, P);
  k_scan   <<<1,                256, 0, stream>>>(counts, offsets, cursor, N);
  k_scatter<<<(P + 255)/256,    256, 0, stream>>>(centers, cursor, perm, P);
  k_edge   <<<(P*16 + 255)/256, 256, 0, stream>>>(sh, rb, perm, nbrs, edgeP, nbP, P);
  k_inv    <<<N,                256, 0, stream>>>(sh, rb, cemb, nbrs, offsets, perm, featsA);
  k_tp     <<<N,                256, 0, stream>>>(featsA, cg_d, cemb);
  k_eq2    <<<N,                512, 0, stream>>>(edgeP, nbP, offsets, featsA, featsB, cg_d);
  k_tp     <<<N,                256, 0, stream>>>(featsB, cg_d, cemb);
  k_energy <<<(N + 3)/4,        256, 0, stream>>>(featsB, wE, bE, (float*)d_out, N);
}